// Round 2
// baseline (200.715 us; speedup 1.0000x reference)
//
#include <hip/hip_runtime.h>
#include <hip/hip_bf16.h>

typedef __bf16 bf16;
typedef __bf16 bf16x8 __attribute__((ext_vector_type(8)));
typedef float f32x4 __attribute__((ext_vector_type(4)));

#define MFMA_16x16x32(A, B, C) __builtin_amdgcn_mfma_f32_16x16x32_bf16(A, B, C, 0, 0, 0)

static_assert(sizeof(bf16x8) == 16, "bf16x8 must be 16B");

// ---------------------------------------------------------------------------
// Kernel 0: cast + transpose the three weight matrices to bf16:
//   Wt[p][h][c] = W_p[c][h],  p in {q,k,v}, h<64, c<1024.
// ---------------------------------------------------------------------------
__global__ __launch_bounds__(256) void wtrans_kernel(
    const float* __restrict__ Wq, const float* __restrict__ Wk,
    const float* __restrict__ Wv, bf16* __restrict__ Wt)
{
  int idx = blockIdx.x * 256 + threadIdx.x;   // 3*64*1024 = 196608 total
  int p = idx >> 16;
  int rem = idx & 65535;
  int h = rem >> 10;
  int c = rem & 1023;
  const float* W = (p == 0) ? Wq : (p == 1) ? Wk : Wv;
  Wt[idx] = (bf16)W[c * 64 + h];
}

// ---------------------------------------------------------------------------
// Kernel 1: projections via 16x16x32 bf16 MFMA — barrier-free version.
//   blockIdx.y == 0 : Q = q @ Wq
//   blockIdx.y == 1 : K = k @ Wk, V = k @ Wv (one read of k for both;
//                     V stored transposed Vt[b][h][t] for the PV MFMA)
// 64-row M tile, 256 threads = 4 waves x 16 rows. No LDS, no barriers:
// A-fragments read f32 from global (L3-fed) + cast; B-fragments read bf16
// straight from the L2-resident transposed weights. A is software-prefetched
// one k-step ahead. Grid = 1024 blocks -> 4 blocks/CU -> 16 waves/CU cap.
// ---------------------------------------------------------------------------
__global__ __launch_bounds__(256) void proj_kernel(
    const float* __restrict__ qin, const float* __restrict__ kin,
    const bf16* __restrict__ Wt,
    bf16* __restrict__ Qb, bf16* __restrict__ Kb, bf16* __restrict__ Vtb)
{
  const int p = blockIdx.y;              // 0: Q   1: K+V
  const int m0 = blockIdx.x * 64;

  const int tid = threadIdx.x;
  const int lane = tid & 63;
  const int w = tid >> 6;
  const int g = lane >> 4;
  const int r = lane & 15;

  const float* A = (p == 0) ? qin : kin;
  const float* ap_base = A + (size_t)(m0 + w * 16 + r) * 1024 + g * 8;

  const bf16* W0 = Wt + (size_t)((p == 0) ? 0 : 1) * 65536 + (size_t)r * 1024 + g * 8;
  const bf16* W1 = Wt + (size_t)2 * 65536 + (size_t)r * 1024 + g * 8;

  f32x4 acc0[4], acc1[4];
  #pragma unroll
  for (int cf = 0; cf < 4; cf++) {
    acc0[cf] = (f32x4){0.f, 0.f, 0.f, 0.f};
    acc1[cf] = (f32x4){0.f, 0.f, 0.f, 0.f};
  }

  // prefetch k0 = 0
  float4 a0 = *(const float4*)(ap_base);
  float4 a1 = *(const float4*)(ap_base + 4);
  float4 a2 = *(const float4*)(ap_base + 32);
  float4 a3 = *(const float4*)(ap_base + 36);

  for (int k0 = 0; k0 < 1024; k0 += 64) {
    bf16x8 af0 = (bf16x8){(bf16)a0.x, (bf16)a0.y, (bf16)a0.z, (bf16)a0.w,
                          (bf16)a1.x, (bf16)a1.y, (bf16)a1.z, (bf16)a1.w};
    bf16x8 af1 = (bf16x8){(bf16)a2.x, (bf16)a2.y, (bf16)a2.z, (bf16)a2.w,
                          (bf16)a3.x, (bf16)a3.y, (bf16)a3.z, (bf16)a3.w};

    // prefetch next k-step's A while this step's B loads + MFMAs run
    if (k0 + 64 < 1024) {
      const float* apn = ap_base + k0 + 64;
      a0 = *(const float4*)(apn);
      a1 = *(const float4*)(apn + 4);
      a2 = *(const float4*)(apn + 32);
      a3 = *(const float4*)(apn + 36);
    }

    #pragma unroll
    for (int cf = 0; cf < 4; cf++) {
      const bf16* b0p = W0 + (size_t)cf * 16384 + k0;   // Wt row cf*16+r
      bf16x8 b00 = *(const bf16x8*)(b0p);
      bf16x8 b01 = *(const bf16x8*)(b0p + 32);
      acc0[cf] = MFMA_16x16x32(af0, b00, acc0[cf]);
      acc0[cf] = MFMA_16x16x32(af1, b01, acc0[cf]);
      if (p == 1) {
        const bf16* b1p = W1 + (size_t)cf * 16384 + k0;
        bf16x8 b10 = *(const bf16x8*)(b1p);
        bf16x8 b11 = *(const bf16x8*)(b1p + 32);
        acc1[cf] = MFMA_16x16x32(af0, b10, acc1[cf]);
        acc1[cf] = MFMA_16x16x32(af1, b11, acc1[cf]);
      }
    }
  }

  // --- epilogue: C/D layout row=(l>>4)*4+j, col=l&15 ---
  #pragma unroll
  for (int cf = 0; cf < 4; cf++) {
    #pragma unroll
    for (int j = 0; j < 4; j++) {
      int rg = m0 + w * 16 + g * 4 + j;
      int col = cf * 16 + r;
      if (p == 0) {
        Qb[(size_t)rg * 64 + col] = (bf16)acc0[cf][j];
      } else {
        Kb[(size_t)rg * 64 + col] = (bf16)acc0[cf][j];
        int bb = rg >> 11, t = rg & 2047;
        Vtb[(size_t)(bb * 64 + col) * 2048 + t] = (bf16)acc1[cf][j];
      }
    }
  }
}

// ---------------------------------------------------------------------------
// Kernel 2: causal flash attention (unchanged from R0).
// Block = 256 threads (4 waves). Q-block = 64 rows (16 per wave), KV tile=64.
// ---------------------------------------------------------------------------
__global__ __launch_bounds__(256) void attn_kernel(
    const bf16* __restrict__ Qb, const bf16* __restrict__ Kb,
    const bf16* __restrict__ Vtb, float* __restrict__ out)
{
  const int qt = (int)(gridDim.x - 1 - blockIdx.x);   // heavy blocks first
  const int b = blockIdx.y;
  const int tid = threadIdx.x;
  const int lane = tid & 63;
  const int w = tid >> 6;
  const int g = lane >> 4;
  const int r = lane & 15;

  __shared__ __align__(16) bf16 Ks[64][80];
  __shared__ __align__(16) bf16 Vs[64][80];
  __shared__ __align__(16) bf16 Ps[4][16][80];

  const int q0 = qt * 64 + w * 16;   // wave's first q-row
  const bf16* qp = Qb + (size_t)(b * 2048 + q0 + r) * 64 + g * 8;
  const bf16x8 qf0 = *(const bf16x8*)qp;
  const bf16x8 qf1 = *(const bf16x8*)(qp + 32);

  f32x4 acc_o[4];
  #pragma unroll
  for (int hf = 0; hf < 4; hf++) acc_o[hf] = (f32x4){0.f, 0.f, 0.f, 0.f};
  float m_r[4] = {-1e30f, -1e30f, -1e30f, -1e30f};
  float l_r[4] = {0.f, 0.f, 0.f, 0.f};
  const float scale = 0.03125f;   // 1/sqrt(1024)

  const int sh = tid >> 2;
  const int sc = (tid & 3) * 16;

  for (int kv = 0; kv <= qt; kv++) {
    // --- stage K tile [64 s][64 h] and V^T tile [64 h][64 s] ---
    {
      const bf16* kp = Kb + (size_t)(b * 2048 + kv * 64 + sh) * 64 + sc;
      *(bf16x8*)&Ks[sh][sc]     = *(const bf16x8*)kp;
      *(bf16x8*)&Ks[sh][sc + 8] = *(const bf16x8*)(kp + 8);
      const bf16* vp = Vtb + (size_t)(b * 64 + sh) * 2048 + kv * 64 + sc;
      *(bf16x8*)&Vs[sh][sc]     = *(const bf16x8*)vp;
      *(bf16x8*)&Vs[sh][sc + 8] = *(const bf16x8*)(vp + 8);
    }
    __syncthreads();

    // --- S = Q K^T : 16x64 per wave ---
    f32x4 s[4];
    #pragma unroll
    for (int cf = 0; cf < 4; cf++) {
      bf16x8 kf0 = *(const bf16x8*)&Ks[cf * 16 + r][g * 8];
      bf16x8 kf1 = *(const bf16x8*)&Ks[cf * 16 + r][32 + g * 8];
      f32x4 t = (f32x4){0.f, 0.f, 0.f, 0.f};
      t = MFMA_16x16x32(qf0, kf0, t);
      t = MFMA_16x16x32(qf1, kf1, t);
      s[cf] = t;
    }

    // --- scale + causal mask + online softmax ---
    const bool diag = (kv == qt);
    float pm[4] = {-1e30f, -1e30f, -1e30f, -1e30f};
    #pragma unroll
    for (int cf = 0; cf < 4; cf++) {
      #pragma unroll
      for (int j = 0; j < 4; j++) {
        float v = s[cf][j] * scale;
        if (diag && (cf * 16 + r) > (w * 16 + g * 4 + j)) v = -1e30f;
        s[cf][j] = v;
        pm[j] = fmaxf(pm[j], v);
      }
    }
    #pragma unroll
    for (int j = 0; j < 4; j++) {
      #pragma unroll
      for (int msk = 1; msk < 16; msk <<= 1)
        pm[j] = fmaxf(pm[j], __shfl_xor(pm[j], msk, 64));
    }
    float corr[4];
    #pragma unroll
    for (int j = 0; j < 4; j++) {
      float mn = fmaxf(m_r[j], pm[j]);
      corr[j] = __expf(m_r[j] - mn);
      m_r[j] = mn;
    }
    float rs[4] = {0.f, 0.f, 0.f, 0.f};
    #pragma unroll
    for (int cf = 0; cf < 4; cf++) {
      #pragma unroll
      for (int j = 0; j < 4; j++) {
        float pv = __expf(s[cf][j] - m_r[j]);
        s[cf][j] = pv;
        rs[j] += pv;
      }
    }
    #pragma unroll
    for (int j = 0; j < 4; j++) {
      #pragma unroll
      for (int msk = 1; msk < 16; msk <<= 1)
        rs[j] += __shfl_xor(rs[j], msk, 64);
      l_r[j] = l_r[j] * corr[j] + rs[j];
    }
    #pragma unroll
    for (int hf = 0; hf < 4; hf++)
      #pragma unroll
      for (int j = 0; j < 4; j++)
        acc_o[hf][j] *= corr[j];

    // --- P (C-layout) -> LDS -> A-layout fragments ---
    #pragma unroll
    for (int cf = 0; cf < 4; cf++)
      #pragma unroll
      for (int j = 0; j < 4; j++)
        Ps[w][g * 4 + j][cf * 16 + r] = (bf16)s[cf][j];

    __syncthreads();

    // --- O += P V ---
    #pragma unroll
    for (int ss = 0; ss < 2; ss++) {
      bf16x8 pf = *(const bf16x8*)&Ps[w][r][ss * 32 + g * 8];
      #pragma unroll
      for (int hf = 0; hf < 4; hf++) {
        bf16x8 vf = *(const bf16x8*)&Vs[hf * 16 + r][ss * 32 + g * 8];
        acc_o[hf] = MFMA_16x16x32(pf, vf, acc_o[hf]);
      }
    }
    __syncthreads();   // before next tile's staging overwrites Ks/Vs
  }

  // --- epilogue: divide by softmax denom, write f32 ---
  float inv[4];
  #pragma unroll
  for (int j = 0; j < 4; j++) inv[j] = 1.0f / l_r[j];
  const size_t ob = (size_t)(b * 2048 + q0) * 64;
  #pragma unroll
  for (int hf = 0; hf < 4; hf++)
    #pragma unroll
    for (int j = 0; j < 4; j++)
      out[ob + (size_t)(g * 4 + j) * 64 + hf * 16 + r] = acc_o[hf][j] * inv[j];
}

// ---------------------------------------------------------------------------
extern "C" void kernel_launch(void* const* d_in, const int* in_sizes, int n_in,
                              void* d_out, int out_size, void* d_ws, size_t ws_size,
                              hipStream_t stream)
{
  const float* q  = (const float*)d_in[0];
  const float* k  = (const float*)d_in[1];
  const float* Wq = (const float*)d_in[2];
  const float* Wk = (const float*)d_in[3];
  const float* Wv = (const float*)d_in[4];
  float* out = (float*)d_out;

  char* ws = (char*)d_ws;
  bf16* Qb  = (bf16*)(ws);                      // [16*2048][64] bf16, 4MB
  bf16* Kb  = (bf16*)(ws + (4u << 20));         // [16*2048][64] bf16, 4MB
  bf16* Vtb = (bf16*)(ws + (8u << 20));         // [16][64][2048] bf16, 4MB
  bf16* Wt  = (bf16*)(ws + (12u << 20));        // [3][64][1024] bf16, 384KB

  hipLaunchKernelGGL(wtrans_kernel, dim3(768), dim3(256), 0, stream,
                     Wq, Wk, Wv, Wt);
  hipLaunchKernelGGL(proj_kernel, dim3(512, 2), dim3(256), 0, stream,
                     q, k, Wt, Qb, Kb, Vtb);
  hipLaunchKernelGGL(attn_kernel, dim3(32, 16), dim3(256), 0, stream,
                     Qb, Kb, Vtb, out);
}

// Round 3
// 127.949 us; speedup vs baseline: 1.5687x; 1.5687x over previous
//
#include <hip/hip_runtime.h>
#include <hip/hip_bf16.h>

typedef __bf16 bf16;
typedef __bf16 bf16x8 __attribute__((ext_vector_type(8)));
typedef float f32x4 __attribute__((ext_vector_type(4)));

#define MFMA_16x16x32(A, B, C) __builtin_amdgcn_mfma_f32_16x16x32_bf16(A, B, C, 0, 0, 0)

static_assert(sizeof(bf16x8) == 16, "bf16x8 must be 16B");

// async 16B global -> LDS DMA (global_load_lds_dwordx4)
__device__ __forceinline__ void gld16(void* lds, const void* g) {
  __builtin_amdgcn_global_load_lds(
      (const __attribute__((address_space(1))) unsigned int*)g,
      (__attribute__((address_space(3))) unsigned int*)lds, 16, 0, 0);
}

// ---------------------------------------------------------------------------
// Kernel 0: cast + transpose the three weight matrices to bf16:
//   Wt[p][h][c] = W_p[c][h],  p in {q,k,v}, h<64, c<1024.
// ---------------------------------------------------------------------------
__global__ __launch_bounds__(256) void wtrans_kernel(
    const float* __restrict__ Wq, const float* __restrict__ Wk,
    const float* __restrict__ Wv, bf16* __restrict__ Wt)
{
  int idx = blockIdx.x * 256 + threadIdx.x;   // 3*64*1024 = 196608 total
  int p = idx >> 16;
  int rem = idx & 65535;
  int h = rem >> 10;
  int c = rem & 1023;
  const float* W = (p == 0) ? Wq : (p == 1) ? Wk : Wv;
  Wt[idx] = (bf16)W[c * 64 + h];
}

// ---------------------------------------------------------------------------
// Kernel 1: projections, m97-style DMA-staged MFMA GEMM.
//   blockIdx.y == 0 : Q = q @ Wq
//   blockIdx.y == 1 : K = k @ Wk, V = k @ Wv  (one read of k for both;
//                     V stored transposed Vt[b][h][t] for the PV MFMA)
// BM=128 rows, BK=32, double-buffered LDS. A staged as f32 via
// global_load_lds (16B, 4 issues/thread/step -> deep DMA queue = high MLP);
// B tiles DMA-staged the same way. One __syncthreads per K-step (the
// compiler's vmcnt drain at the barrier is the DMA completion guarantee).
// 4 waves x 32 rows (rf=2), cf=4. LDS 48KB -> 2 blocks/CU (grid = 2/CU).
// Un-swizzled LDS reads are N-way bank conflicted but off the critical path.
// ---------------------------------------------------------------------------
__global__ __launch_bounds__(256, 2) void proj_kernel(
    const float* __restrict__ qin, const float* __restrict__ kin,
    const bf16* __restrict__ Wt,
    bf16* __restrict__ Qb, bf16* __restrict__ Kb, bf16* __restrict__ Vtb)
{
  const int p = blockIdx.y;              // 0: Q   1: K+V
  const int m0 = blockIdx.x * 128;
  const float* A = (p == 0) ? qin : kin;
  const int nmat = (p == 0) ? 1 : 2;

  __shared__ __align__(16) float As[2][128 * 32];       // 2 x 16 KB
  __shared__ __align__(16) bf16  Bs[2][2][64 * 32];     // 2 x 2 x 4 KB

  const int tid = threadIdx.x;
  const int lane = tid & 63;
  const int w = tid >> 6;
  const int g = lane >> 4;
  const int r = lane & 15;

  f32x4 acc[2][2][4];   // [mat][rf][cf]
  #pragma unroll
  for (int mt = 0; mt < 2; mt++)
    #pragma unroll
    for (int rf = 0; rf < 2; rf++)
      #pragma unroll
      for (int cf = 0; cf < 4; cf++)
        acc[mt][rf][cf] = (f32x4){0.f, 0.f, 0.f, 0.f};

  // B staging geometry: 64 rows x 32 cols bf16 = 256 x 16B chunks
  const int brow = tid >> 2;
  const int bch = tid & 3;

  // --- staging: issue all DMAs for K-step k0 into buffer `buf` ---
  auto stage = [&](int buf, int k0) {
    // A tile: 128 rows x 32 f32 = 1024 x 16B chunks, 4 per thread.
    // LDS dest is linear (chunk ci at byte ci*16); per instr the wave's
    // lanes are consecutive chunks -> wave-uniform base + lane*16. OK.
    #pragma unroll
    for (int i = 0; i < 4; i++) {
      int ci = i * 256 + tid;
      int row = ci >> 3, ch = ci & 7;
      gld16(&As[buf][ci * 4],
            A + (size_t)(m0 + row) * 1024 + k0 + ch * 4);
    }
    #pragma unroll
    for (int mt = 0; mt < 2; mt++) {
      if (mt < nmat) {
        const bf16* src = Wt + (size_t)((p == 0) ? 0 : 1 + mt) * 65536
                          + (size_t)brow * 1024 + k0 + bch * 8;
        gld16(&Bs[buf][mt][(size_t)tid * 8], src);
      }
    }
  };

  stage(0, 0);

  for (int it = 0; it < 32; ++it) {
    const int cur = it & 1;
    __syncthreads();                       // vmcnt drain: buf[cur] ready
    if (it + 1 < 32) stage(cur ^ 1, (it + 1) * 32);

    // A fragments: ds_read f32, cast to bf16
    bf16x8 af[2];
    #pragma unroll
    for (int rf = 0; rf < 2; rf++) {
      const float* ap = &As[cur][(w * 32 + rf * 16 + r) * 32 + g * 8];
      float4 lo = *(const float4*)ap;
      float4 hi = *(const float4*)(ap + 4);
      af[rf] = (bf16x8){(bf16)lo.x, (bf16)lo.y, (bf16)lo.z, (bf16)lo.w,
                        (bf16)hi.x, (bf16)hi.y, (bf16)hi.z, (bf16)hi.w};
    }

    #pragma unroll
    for (int mt = 0; mt < 2; mt++) {
      if (mt < nmat) {
        #pragma unroll
        for (int cf = 0; cf < 4; cf++) {
          bf16x8 bfr = *(const bf16x8*)&Bs[cur][mt][(cf * 16 + r) * 32 + g * 8];
          #pragma unroll
          for (int rf = 0; rf < 2; rf++)
            acc[mt][rf][cf] = MFMA_16x16x32(af[rf], bfr, acc[mt][rf][cf]);
        }
      }
    }
  }

  // --- epilogue: C/D layout row=(l>>4)*4+j, col=l&15 ---
  #pragma unroll
  for (int rf = 0; rf < 2; rf++) {
    #pragma unroll
    for (int cf = 0; cf < 4; cf++) {
      #pragma unroll
      for (int j = 0; j < 4; j++) {
        int rg = m0 + w * 32 + rf * 16 + g * 4 + j;
        int col = cf * 16 + r;
        if (p == 0) {
          Qb[(size_t)rg * 64 + col] = (bf16)acc[0][rf][cf][j];
        } else {
          Kb[(size_t)rg * 64 + col] = (bf16)acc[0][rf][cf][j];
          int bb = rg >> 11, t = rg & 2047;
          Vtb[(size_t)(bb * 64 + col) * 2048 + t] = (bf16)acc[1][rf][cf][j];
        }
      }
    }
  }
}

// ---------------------------------------------------------------------------
// Kernel 2: causal flash attention (unchanged).
// Block = 256 threads (4 waves). Q-block = 64 rows (16 per wave), KV tile=64.
// ---------------------------------------------------------------------------
__global__ __launch_bounds__(256) void attn_kernel(
    const bf16* __restrict__ Qb, const bf16* __restrict__ Kb,
    const bf16* __restrict__ Vtb, float* __restrict__ out)
{
  const int qt = (int)(gridDim.x - 1 - blockIdx.x);   // heavy blocks first
  const int b = blockIdx.y;
  const int tid = threadIdx.x;
  const int lane = tid & 63;
  const int w = tid >> 6;
  const int g = lane >> 4;
  const int r = lane & 15;

  __shared__ __align__(16) bf16 Ks[64][80];
  __shared__ __align__(16) bf16 Vs[64][80];
  __shared__ __align__(16) bf16 Ps[4][16][80];

  const int q0 = qt * 64 + w * 16;   // wave's first q-row
  const bf16* qp = Qb + (size_t)(b * 2048 + q0 + r) * 64 + g * 8;
  const bf16x8 qf0 = *(const bf16x8*)qp;
  const bf16x8 qf1 = *(const bf16x8*)(qp + 32);

  f32x4 acc_o[4];
  #pragma unroll
  for (int hf = 0; hf < 4; hf++) acc_o[hf] = (f32x4){0.f, 0.f, 0.f, 0.f};
  float m_r[4] = {-1e30f, -1e30f, -1e30f, -1e30f};
  float l_r[4] = {0.f, 0.f, 0.f, 0.f};
  const float scale = 0.03125f;   // 1/sqrt(1024)

  const int sh = tid >> 2;
  const int sc = (tid & 3) * 16;

  for (int kv = 0; kv <= qt; kv++) {
    // --- stage K tile [64 s][64 h] and V^T tile [64 h][64 s] ---
    {
      const bf16* kp = Kb + (size_t)(b * 2048 + kv * 64 + sh) * 64 + sc;
      *(bf16x8*)&Ks[sh][sc]     = *(const bf16x8*)kp;
      *(bf16x8*)&Ks[sh][sc + 8] = *(const bf16x8*)(kp + 8);
      const bf16* vp = Vtb + (size_t)(b * 64 + sh) * 2048 + kv * 64 + sc;
      *(bf16x8*)&Vs[sh][sc]     = *(const bf16x8*)vp;
      *(bf16x8*)&Vs[sh][sc + 8] = *(const bf16x8*)(vp + 8);
    }
    __syncthreads();

    // --- S = Q K^T : 16x64 per wave ---
    f32x4 s[4];
    #pragma unroll
    for (int cf = 0; cf < 4; cf++) {
      bf16x8 kf0 = *(const bf16x8*)&Ks[cf * 16 + r][g * 8];
      bf16x8 kf1 = *(const bf16x8*)&Ks[cf * 16 + r][32 + g * 8];
      f32x4 t = (f32x4){0.f, 0.f, 0.f, 0.f};
      t = MFMA_16x16x32(qf0, kf0, t);
      t = MFMA_16x16x32(qf1, kf1, t);
      s[cf] = t;
    }

    // --- scale + causal mask + online softmax ---
    const bool diag = (kv == qt);
    float pm[4] = {-1e30f, -1e30f, -1e30f, -1e30f};
    #pragma unroll
    for (int cf = 0; cf < 4; cf++) {
      #pragma unroll
      for (int j = 0; j < 4; j++) {
        float v = s[cf][j] * scale;
        if (diag && (cf * 16 + r) > (w * 16 + g * 4 + j)) v = -1e30f;
        s[cf][j] = v;
        pm[j] = fmaxf(pm[j], v);
      }
    }
    #pragma unroll
    for (int j = 0; j < 4; j++) {
      #pragma unroll
      for (int msk = 1; msk < 16; msk <<= 1)
        pm[j] = fmaxf(pm[j], __shfl_xor(pm[j], msk, 64));
    }
    float corr[4];
    #pragma unroll
    for (int j = 0; j < 4; j++) {
      float mn = fmaxf(m_r[j], pm[j]);
      corr[j] = __expf(m_r[j] - mn);
      m_r[j] = mn;
    }
    float rs[4] = {0.f, 0.f, 0.f, 0.f};
    #pragma unroll
    for (int cf = 0; cf < 4; cf++) {
      #pragma unroll
      for (int j = 0; j < 4; j++) {
        float pv = __expf(s[cf][j] - m_r[j]);
        s[cf][j] = pv;
        rs[j] += pv;
      }
    }
    #pragma unroll
    for (int j = 0; j < 4; j++) {
      #pragma unroll
      for (int msk = 1; msk < 16; msk <<= 1)
        rs[j] += __shfl_xor(rs[j], msk, 64);
      l_r[j] = l_r[j] * corr[j] + rs[j];
    }
    #pragma unroll
    for (int hf = 0; hf < 4; hf++)
      #pragma unroll
      for (int j = 0; j < 4; j++)
        acc_o[hf][j] *= corr[j];

    // --- P (C-layout) -> LDS -> A-layout fragments ---
    #pragma unroll
    for (int cf = 0; cf < 4; cf++)
      #pragma unroll
      for (int j = 0; j < 4; j++)
        Ps[w][g * 4 + j][cf * 16 + r] = (bf16)s[cf][j];

    __syncthreads();

    // --- O += P V ---
    #pragma unroll
    for (int ss = 0; ss < 2; ss++) {
      bf16x8 pf = *(const bf16x8*)&Ps[w][r][ss * 32 + g * 8];
      #pragma unroll
      for (int hf = 0; hf < 4; hf++) {
        bf16x8 vf = *(const bf16x8*)&Vs[hf * 16 + r][ss * 32 + g * 8];
        acc_o[hf] = MFMA_16x16x32(pf, vf, acc_o[hf]);
      }
    }
    __syncthreads();   // before next tile's staging overwrites Ks/Vs
  }

  // --- epilogue: divide by softmax denom, write f32 ---
  float inv[4];
  #pragma unroll
  for (int j = 0; j < 4; j++) inv[j] = 1.0f / l_r[j];
  const size_t ob = (size_t)(b * 2048 + q0) * 64;
  #pragma unroll
  for (int hf = 0; hf < 4; hf++)
    #pragma unroll
    for (int j = 0; j < 4; j++)
      out[ob + (size_t)(g * 4 + j) * 64 + hf * 16 + r] = acc_o[hf][j] * inv[j];
}

// ---------------------------------------------------------------------------
extern "C" void kernel_launch(void* const* d_in, const int* in_sizes, int n_in,
                              void* d_out, int out_size, void* d_ws, size_t ws_size,
                              hipStream_t stream)
{
  const float* q  = (const float*)d_in[0];
  const float* k  = (const float*)d_in[1];
  const float* Wq = (const float*)d_in[2];
  const float* Wk = (const float*)d_in[3];
  const float* Wv = (const float*)d_in[4];
  float* out = (float*)d_out;

  char* ws = (char*)d_ws;
  bf16* Qb  = (bf16*)(ws);                      // [16*2048][64] bf16, 4MB
  bf16* Kb  = (bf16*)(ws + (4u << 20));         // [16*2048][64] bf16, 4MB
  bf16* Vtb = (bf16*)(ws + (8u << 20));         // [16][64][2048] bf16, 4MB
  bf16* Wt  = (bf16*)(ws + (12u << 20));        // [3][64][1024] bf16, 384KB

  hipLaunchKernelGGL(wtrans_kernel, dim3(768), dim3(256), 0, stream,
                     Wq, Wk, Wv, Wt);
  hipLaunchKernelGGL(proj_kernel, dim3(256, 2), dim3(256), 0, stream,
                     q, k, Wt, Qb, Kb, Vtb);
  hipLaunchKernelGGL(attn_kernel, dim3(32, 16), dim3(256), 0, stream,
                     Qb, Kb, Vtb, out);
}

// Round 4
// 127.921 us; speedup vs baseline: 1.5691x; 1.0002x over previous
//
#include <hip/hip_runtime.h>
#include <hip/hip_bf16.h>

typedef __bf16 bf16;
typedef __bf16 bf16x8 __attribute__((ext_vector_type(8)));
typedef float f32x4 __attribute__((ext_vector_type(4)));

#define MFMA_16x16x32(A, B, C) __builtin_amdgcn_mfma_f32_16x16x32_bf16(A, B, C, 0, 0, 0)

static_assert(sizeof(bf16x8) == 16, "bf16x8 must be 16B");

// async 16B global -> LDS DMA (global_load_lds_dwordx4)
__device__ __forceinline__ void gld16(void* lds, const void* g) {
  __builtin_amdgcn_global_load_lds(
      (const __attribute__((address_space(1))) unsigned int*)g,
      (__attribute__((address_space(3))) unsigned int*)lds, 16, 0, 0);
}

// ---------------------------------------------------------------------------
// Kernel 0: cast + transpose the three weight matrices to bf16:
//   Wt[p][h][c] = W_p[c][h],  p in {q,k,v}, h<64, c<1024.
// ---------------------------------------------------------------------------
__global__ __launch_bounds__(256) void wtrans_kernel(
    const float* __restrict__ Wq, const float* __restrict__ Wk,
    const float* __restrict__ Wv, bf16* __restrict__ Wt)
{
  int idx = blockIdx.x * 256 + threadIdx.x;   // 3*64*1024 = 196608 total
  int p = idx >> 16;
  int rem = idx & 65535;
  int h = rem >> 10;
  int c = rem & 1023;
  const float* W = (p == 0) ? Wq : (p == 1) ? Wk : Wv;
  Wt[idx] = (bf16)W[c * 64 + h];
}

// ---------------------------------------------------------------------------
// Kernel 1: projections — 3-deep DMA pipeline with COUNTED vmcnt (T3+T4).
//   blockIdx.y == 0 : Q = q @ Wq
//   blockIdx.y == 1 : K = k @ Wk, V = k @ Wv  (V stored transposed)
// BM=128, BK=32, triple-buffered LDS (72 KB). Each stage issues exactly 6
// global_load_lds_dwordx4 per thread (4 A-f32 chunks + 2 B; p=0 duplicates
// the 2nd B-load to keep vmcnt accounting uniform). Main loop waits
// s_waitcnt vmcnt(12) (= the 2 newer in-flight tiles) + raw s_barrier —
// NEVER drains to 0, so loads stay in flight across barriers. Re-staging of
// a consumed buffer is guarded by lgkmcnt(0)+s_barrier (WAR). LDS accesses
// are XOR-swizzled BOTH sides (pre-swizzled global source + swizzled
// ds_read address, linear DMA dest) to kill the 16-way A / 8-way B bank
// conflicts that land on the critical path once the drain-stall is gone.
// ---------------------------------------------------------------------------
__global__ __launch_bounds__(256, 2) void proj_kernel(
    const float* __restrict__ qin, const float* __restrict__ kin,
    const bf16* __restrict__ Wt,
    bf16* __restrict__ Qb, bf16* __restrict__ Kb, bf16* __restrict__ Vtb)
{
  const int p = blockIdx.y;              // 0: Q   1: K+V
  const int m0 = blockIdx.x * 128;
  const float* A = (p == 0) ? qin : kin;
  const int nmat = (p == 0) ? 1 : 2;
  const int mat0 = (p == 0) ? 0 : 1;
  const int mat1 = (p == 0) ? 0 : 2;     // p=0: dummy dup keeps 6 vmem/stage

  __shared__ __align__(16) float As[3][128 * 32];     // 3 x 16 KB
  __shared__ __align__(16) bf16  Bs[3][2][64 * 32];   // 3 x 2 x 4 KB

  const int tid = threadIdx.x;
  const int lane = tid & 63;
  const int w = tid >> 6;
  const int g = lane >> 4;
  const int r = lane & 15;

  f32x4 acc[2][2][4];   // [mat][rf][cf]
  #pragma unroll
  for (int mt = 0; mt < 2; mt++)
    #pragma unroll
    for (int rf = 0; rf < 2; rf++)
      #pragma unroll
      for (int cf = 0; cf < 4; cf++)
        acc[mt][rf][cf] = (f32x4){0.f, 0.f, 0.f, 0.f};

  // --- stage: 6 gld16/thread; sources pre-swizzled so LDS stays linear ---
  auto stage = [&](int buf, int k0) {
    #pragma unroll
    for (int i = 0; i < 4; i++) {
      int ci = i * 256 + tid;            // 16B chunk id, 0..1023
      int row = ci >> 3, pch = ci & 7;   // physical chunk within row
      // physical chunk pch holds logical chunk (pch ^ (row&7))
      gld16(&As[buf][ci * 4],
            A + (size_t)(m0 + row) * 1024 + k0 + ((pch ^ (row & 7)) << 2));
    }
    {
      int brow = tid >> 2, bch = tid & 3;
      int lch = bch ^ ((brow >> 1) & 3);
      const bf16* s0 = Wt + (size_t)mat0 * 65536 + (size_t)brow * 1024 + k0 + (lch << 3);
      const bf16* s1 = Wt + (size_t)mat1 * 65536 + (size_t)brow * 1024 + k0 + (lch << 3);
      gld16(&Bs[buf][0][tid * 8], s0);
      gld16(&Bs[buf][1][tid * 8], s1);
    }
  };

  // --- compute one K-step from buffer `cur` (swizzled ds_read addrs) ---
  auto compute = [&](int cur) {
    bf16x8 af[2];
    #pragma unroll
    for (int rf = 0; rf < 2; rf++) {
      int arow = w * 32 + rf * 16 + r;
      const float* base = &As[cur][arow * 32];
      float4 lo = *(const float4*)(base + ((( 2 * g )     ^ (arow & 7)) << 2));
      float4 hi = *(const float4*)(base + ((( 2 * g + 1 ) ^ (arow & 7)) << 2));
      af[rf] = (bf16x8){(bf16)lo.x, (bf16)lo.y, (bf16)lo.z, (bf16)lo.w,
                        (bf16)hi.x, (bf16)hi.y, (bf16)hi.z, (bf16)hi.w};
    }
    #pragma unroll
    for (int mt = 0; mt < 2; mt++) {
      if (mt < nmat) {
        #pragma unroll
        for (int cf = 0; cf < 4; cf++) {
          int hrow = cf * 16 + r;
          bf16x8 bfr = *(const bf16x8*)
              &Bs[cur][mt][hrow * 32 + ((g ^ ((hrow >> 1) & 3)) << 3)];
          #pragma unroll
          for (int rf = 0; rf < 2; rf++)
            acc[mt][rf][cf] = MFMA_16x16x32(af[rf], bfr, acc[mt][rf][cf]);
        }
      }
    }
  };

  // --- prologue: 3 tiles in flight (18 vmem instrs/wave) ---
  stage(0, 0);
  stage(1, 32);
  stage(2, 64);

  int cur = 0;
  for (int it = 0; it < 30; ++it) {
    // tile `it` complete when <=12 newer vmem instrs remain in flight
    asm volatile("s_waitcnt vmcnt(12)\n\ts_barrier" ::: "memory");
    compute(cur);
    // all waves done reading buf `cur` before its DMAs are re-issued
    asm volatile("s_waitcnt lgkmcnt(0)\n\ts_barrier" ::: "memory");
    if (it < 29) stage(cur, (it + 3) * 32);
    cur = (cur == 2) ? 0 : cur + 1;
  }
  // it = 30 (buf 0): only tile 31's 6 instrs may remain
  asm volatile("s_waitcnt vmcnt(6)\n\ts_barrier" ::: "memory");
  compute(0);
  // it = 31 (buf 1): drain
  asm volatile("s_waitcnt vmcnt(0)\n\ts_barrier" ::: "memory");
  compute(1);

  // --- epilogue: C/D layout row=(l>>4)*4+j, col=l&15 ---
  #pragma unroll
  for (int rf = 0; rf < 2; rf++) {
    #pragma unroll
    for (int cf = 0; cf < 4; cf++) {
      #pragma unroll
      for (int j = 0; j < 4; j++) {
        int rg = m0 + w * 32 + rf * 16 + g * 4 + j;
        int col = cf * 16 + r;
        if (p == 0) {
          Qb[(size_t)rg * 64 + col] = (bf16)acc[0][rf][cf][j];
        } else {
          Kb[(size_t)rg * 64 + col] = (bf16)acc[0][rf][cf][j];
          int bb = rg >> 11, t = rg & 2047;
          Vtb[(size_t)(bb * 64 + col) * 2048 + t] = (bf16)acc[1][rf][cf][j];
        }
      }
    }
  }
}

// ---------------------------------------------------------------------------
// Kernel 2: causal flash attention (unchanged).
// Block = 256 threads (4 waves). Q-block = 64 rows (16 per wave), KV tile=64.
// ---------------------------------------------------------------------------
__global__ __launch_bounds__(256) void attn_kernel(
    const bf16* __restrict__ Qb, const bf16* __restrict__ Kb,
    const bf16* __restrict__ Vtb, float* __restrict__ out)
{
  const int qt = (int)(gridDim.x - 1 - blockIdx.x);   // heavy blocks first
  const int b = blockIdx.y;
  const int tid = threadIdx.x;
  const int lane = tid & 63;
  const int w = tid >> 6;
  const int g = lane >> 4;
  const int r = lane & 15;

  __shared__ __align__(16) bf16 Ks[64][80];
  __shared__ __align__(16) bf16 Vs[64][80];
  __shared__ __align__(16) bf16 Ps[4][16][80];

  const int q0 = qt * 64 + w * 16;   // wave's first q-row
  const bf16* qp = Qb + (size_t)(b * 2048 + q0 + r) * 64 + g * 8;
  const bf16x8 qf0 = *(const bf16x8*)qp;
  const bf16x8 qf1 = *(const bf16x8*)(qp + 32);

  f32x4 acc_o[4];
  #pragma unroll
  for (int hf = 0; hf < 4; hf++) acc_o[hf] = (f32x4){0.f, 0.f, 0.f, 0.f};
  float m_r[4] = {-1e30f, -1e30f, -1e30f, -1e30f};
  float l_r[4] = {0.f, 0.f, 0.f, 0.f};
  const float scale = 0.03125f;   // 1/sqrt(1024)

  const int sh = tid >> 2;
  const int sc = (tid & 3) * 16;

  for (int kv = 0; kv <= qt; kv++) {
    // --- stage K tile [64 s][64 h] and V^T tile [64 h][64 s] ---
    {
      const bf16* kp = Kb + (size_t)(b * 2048 + kv * 64 + sh) * 64 + sc;
      *(bf16x8*)&Ks[sh][sc]     = *(const bf16x8*)kp;
      *(bf16x8*)&Ks[sh][sc + 8] = *(const bf16x8*)(kp + 8);
      const bf16* vp = Vtb + (size_t)(b * 64 + sh) * 2048 + kv * 64 + sc;
      *(bf16x8*)&Vs[sh][sc]     = *(const bf16x8*)vp;
      *(bf16x8*)&Vs[sh][sc + 8] = *(const bf16x8*)(vp + 8);
    }
    __syncthreads();

    // --- S = Q K^T : 16x64 per wave ---
    f32x4 s[4];
    #pragma unroll
    for (int cf = 0; cf < 4; cf++) {
      bf16x8 kf0 = *(const bf16x8*)&Ks[cf * 16 + r][g * 8];
      bf16x8 kf1 = *(const bf16x8*)&Ks[cf * 16 + r][32 + g * 8];
      f32x4 t = (f32x4){0.f, 0.f, 0.f, 0.f};
      t = MFMA_16x16x32(qf0, kf0, t);
      t = MFMA_16x16x32(qf1, kf1, t);
      s[cf] = t;
    }

    // --- scale + causal mask + online softmax ---
    const bool diag = (kv == qt);
    float pm[4] = {-1e30f, -1e30f, -1e30f, -1e30f};
    #pragma unroll
    for (int cf = 0; cf < 4; cf++) {
      #pragma unroll
      for (int j = 0; j < 4; j++) {
        float v = s[cf][j] * scale;
        if (diag && (cf * 16 + r) > (w * 16 + g * 4 + j)) v = -1e30f;
        s[cf][j] = v;
        pm[j] = fmaxf(pm[j], v);
      }
    }
    #pragma unroll
    for (int j = 0; j < 4; j++) {
      #pragma unroll
      for (int msk = 1; msk < 16; msk <<= 1)
        pm[j] = fmaxf(pm[j], __shfl_xor(pm[j], msk, 64));
    }
    float corr[4];
    #pragma unroll
    for (int j = 0; j < 4; j++) {
      float mn = fmaxf(m_r[j], pm[j]);
      corr[j] = __expf(m_r[j] - mn);
      m_r[j] = mn;
    }
    float rs[4] = {0.f, 0.f, 0.f, 0.f};
    #pragma unroll
    for (int cf = 0; cf < 4; cf++) {
      #pragma unroll
      for (int j = 0; j < 4; j++) {
        float pv = __expf(s[cf][j] - m_r[j]);
        s[cf][j] = pv;
        rs[j] += pv;
      }
    }
    #pragma unroll
    for (int j = 0; j < 4; j++) {
      #pragma unroll
      for (int msk = 1; msk < 16; msk <<= 1)
        rs[j] += __shfl_xor(rs[j], msk, 64);
      l_r[j] = l_r[j] * corr[j] + rs[j];
    }
    #pragma unroll
    for (int hf = 0; hf < 4; hf++)
      #pragma unroll
      for (int j = 0; j < 4; j++)
        acc_o[hf][j] *= corr[j];

    // --- P (C-layout) -> LDS -> A-layout fragments ---
    #pragma unroll
    for (int cf = 0; cf < 4; cf++)
      #pragma unroll
      for (int j = 0; j < 4; j++)
        Ps[w][g * 4 + j][cf * 16 + r] = (bf16)s[cf][j];

    __syncthreads();

    // --- O += P V ---
    #pragma unroll
    for (int ss = 0; ss < 2; ss++) {
      bf16x8 pf = *(const bf16x8*)&Ps[w][r][ss * 32 + g * 8];
      #pragma unroll
      for (int hf = 0; hf < 4; hf++) {
        bf16x8 vf = *(const bf16x8*)&Vs[hf * 16 + r][ss * 32 + g * 8];
        acc_o[hf] = MFMA_16x16x32(pf, vf, acc_o[hf]);
      }
    }
    __syncthreads();   // before next tile's staging overwrites Ks/Vs
  }

  // --- epilogue: divide by softmax denom, write f32 ---
  float inv[4];
  #pragma unroll
  for (int j = 0; j < 4; j++) inv[j] = 1.0f / l_r[j];
  const size_t ob = (size_t)(b * 2048 + q0) * 64;
  #pragma unroll
  for (int hf = 0; hf < 4; hf++)
    #pragma unroll
    for (int j = 0; j < 4; j++)
      out[ob + (size_t)(g * 4 + j) * 64 + hf * 16 + r] = acc_o[hf][j] * inv[j];
}

// ---------------------------------------------------------------------------
extern "C" void kernel_launch(void* const* d_in, const int* in_sizes, int n_in,
                              void* d_out, int out_size, void* d_ws, size_t ws_size,
                              hipStream_t stream)
{
  const float* q  = (const float*)d_in[0];
  const float* k  = (const float*)d_in[1];
  const float* Wq = (const float*)d_in[2];
  const float* Wk = (const float*)d_in[3];
  const float* Wv = (const float*)d_in[4];
  float* out = (float*)d_out;

  char* ws = (char*)d_ws;
  bf16* Qb  = (bf16*)(ws);                      // [16*2048][64] bf16, 4MB
  bf16* Kb  = (bf16*)(ws + (4u << 20));         // [16*2048][64] bf16, 4MB
  bf16* Vtb = (bf16*)(ws + (8u << 20));         // [16][64][2048] bf16, 4MB
  bf16* Wt  = (bf16*)(ws + (12u << 20));        // [3][64][1024] bf16, 384KB

  hipLaunchKernelGGL(wtrans_kernel, dim3(768), dim3(256), 0, stream,
                     Wq, Wk, Wv, Wt);
  hipLaunchKernelGGL(proj_kernel, dim3(256, 2), dim3(256), 0, stream,
                     q, k, Wt, Qb, Kb, Vtb);
  hipLaunchKernelGGL(attn_kernel, dim3(32, 16), dim3(256), 0, stream,
                     Qb, Kb, Vtb, out);
}